// Round 3
// baseline (324.640 us; speedup 1.0000x reference)
//
#include <hip/hip_runtime.h>
#include <math.h>

#define EPSV 1e-5f

// ---------------------------------------------------------------------------
// K1: combined projection GEMMs, 128-row tiles. blocks 0..511 x, 512..639 z.
// Y[r][n] = sum_c X[r][c]*W[c][n] + bias[n]  (C=256, N=64)
// ---------------------------------------------------------------------------
__global__ __launch_bounds__(256) void gemm_all(
    const float* __restrict__ Xx, const float* __restrict__ Wxp,
    const float* __restrict__ bxp, float* __restrict__ Yx,
    const float* __restrict__ Xz, const float* __restrict__ Wzp,
    const float* __restrict__ bzp, float* __restrict__ Yz)
{
    __shared__ float Xc[16 * 132];   // [cl][row], stride 132 (16B-aligned, bank-rotated)
    __shared__ float Wc[16 * 64];    // [cl][n]
    const int t = threadIdx.x;
    const float *X, *W, *bias; float* Y; long r0;
    if (blockIdx.x < 512) { X = Xx; W = Wxp; bias = bxp; Y = Yx; r0 = (long)blockIdx.x * 128; }
    else                  { X = Xz; W = Wzp; bias = bzp; Y = Yz; r0 = (long)(blockIdx.x - 512) * 128; }

    const int tr = t >> 4, tc = t & 15;   // rows tr*8..+7, cols tc*4..+3
    float4 bv = *(const float4*)(bias + tc * 4);
    float acc[8][4];
#pragma unroll
    for (int i = 0; i < 8; ++i) { acc[i][0]=bv.x; acc[i][1]=bv.y; acc[i][2]=bv.z; acc[i][3]=bv.w; }

    const int lr = t >> 2;            // 0..63 (also lr+64)
    const int lc = (t & 3) * 4;
    const int wl = t >> 4, wj = (t & 15) * 4;
    float4 xv0 = *(const float4*)(X + (r0 + lr) * 256 + lc);
    float4 xv1 = *(const float4*)(X + (r0 + lr + 64) * 256 + lc);
    float4 wv  = *(const float4*)(W + (long)wl * 64 + wj);

    for (int c0 = 0; c0 < 256; c0 += 16) {
        Xc[(lc+0)*132 + lr] = xv0.x; Xc[(lc+1)*132 + lr] = xv0.y;
        Xc[(lc+2)*132 + lr] = xv0.z; Xc[(lc+3)*132 + lr] = xv0.w;
        Xc[(lc+0)*132 + lr+64] = xv1.x; Xc[(lc+1)*132 + lr+64] = xv1.y;
        Xc[(lc+2)*132 + lr+64] = xv1.z; Xc[(lc+3)*132 + lr+64] = xv1.w;
        *(float4*)&Wc[wl * 64 + wj] = wv;
        __syncthreads();
        if (c0 + 16 < 256) {
            xv0 = *(const float4*)(X + (r0 + lr) * 256 + c0 + 16 + lc);
            xv1 = *(const float4*)(X + (r0 + lr + 64) * 256 + c0 + 16 + lc);
            wv  = *(const float4*)(W + (long)(c0 + 16 + wl) * 64 + wj);
        }
#pragma unroll
        for (int cl = 0; cl < 16; ++cl) {
            float4 a0 = *(float4*)&Xc[cl * 132 + tr * 8];
            float4 a1 = *(float4*)&Xc[cl * 132 + tr * 8 + 4];
            float4 b4 = *(float4*)&Wc[cl * 64 + tc * 4];
            acc[0][0]+=a0.x*b4.x; acc[0][1]+=a0.x*b4.y; acc[0][2]+=a0.x*b4.z; acc[0][3]+=a0.x*b4.w;
            acc[1][0]+=a0.y*b4.x; acc[1][1]+=a0.y*b4.y; acc[1][2]+=a0.y*b4.z; acc[1][3]+=a0.y*b4.w;
            acc[2][0]+=a0.z*b4.x; acc[2][1]+=a0.z*b4.y; acc[2][2]+=a0.z*b4.z; acc[2][3]+=a0.z*b4.w;
            acc[3][0]+=a0.w*b4.x; acc[3][1]+=a0.w*b4.y; acc[3][2]+=a0.w*b4.z; acc[3][3]+=a0.w*b4.w;
            acc[4][0]+=a1.x*b4.x; acc[4][1]+=a1.x*b4.y; acc[4][2]+=a1.x*b4.z; acc[4][3]+=a1.x*b4.w;
            acc[5][0]+=a1.y*b4.x; acc[5][1]+=a1.y*b4.y; acc[5][2]+=a1.y*b4.z; acc[5][3]+=a1.y*b4.w;
            acc[6][0]+=a1.z*b4.x; acc[6][1]+=a1.z*b4.y; acc[6][2]+=a1.z*b4.z; acc[6][3]+=a1.z*b4.w;
            acc[7][0]+=a1.w*b4.x; acc[7][1]+=a1.w*b4.y; acc[7][2]+=a1.w*b4.z; acc[7][3]+=a1.w*b4.w;
        }
        __syncthreads();
    }
#pragma unroll
    for (int i = 0; i < 8; ++i) {
        float4 o = make_float4(acc[i][0], acc[i][1], acc[i][2], acc[i][3]);
        *(float4*)(Y + (r0 + tr * 8 + i) * 64 + tc * 4) = o;
    }
}

// ---------------------------------------------------------------------------
// K2: combined correlations, 64-pixel K-chunks (32 barriers for P=1024).
// S[b][n][c] = sum_p Yn[b*P+p][n] * X[b*P+p][c]
// ---------------------------------------------------------------------------
__global__ __launch_bounds__(256) void corr_all(
    const float* __restrict__ xn, const float* __restrict__ xf,
    float* __restrict__ kxr, const float* __restrict__ zc,
    const float* __restrict__ zf, float* __restrict__ kern)
{
    __shared__ float A[64 * 64];     // [p][n]
    __shared__ float Bt[64 * 64];    // [p][c_local]
    const int t = threadIdx.x;
    const float *Yn, *X; float* S; int b, P;
    if (blockIdx.y < 64) { b = blockIdx.y;      Yn = xn; X = xf; S = kxr;  P = 1024; }
    else                 { b = blockIdx.y - 64; Yn = zc; X = zf; S = kern; P = 256;  }
    const int c0 = blockIdx.x * 64;
    const int tn = t >> 4, tc = t & 15;

    float acc[4][4] = {};
    float4 av[4], bv4[4];
#pragma unroll
    for (int i = 0; i < 4; ++i) {
        int idx = t + i * 256; int p = idx >> 4, f4 = (idx & 15) * 4;
        long rb = (long)b * P + p;
        av[i]  = *(const float4*)(Yn + rb * 64 + f4);
        bv4[i] = *(const float4*)(X + rb * 256 + c0 + f4);
    }
    for (int p0 = 0; p0 < P; p0 += 64) {
#pragma unroll
        for (int i = 0; i < 4; ++i) {
            int idx = t + i * 256; int p = idx >> 4, f4 = (idx & 15) * 4;
            *(float4*)&A[p * 64 + f4] = av[i];
            *(float4*)&Bt[p * 64 + f4] = bv4[i];
        }
        __syncthreads();
        if (p0 + 64 < P) {
#pragma unroll
            for (int i = 0; i < 4; ++i) {
                int idx = t + i * 256; int p = idx >> 4, f4 = (idx & 15) * 4;
                long rb = (long)b * P + p0 + 64 + p;
                av[i]  = *(const float4*)(Yn + rb * 64 + f4);
                bv4[i] = *(const float4*)(X + rb * 256 + c0 + f4);
            }
        }
#pragma unroll 16
        for (int p = 0; p < 64; ++p) {
            float4 a  = *(float4*)&A[p * 64 + tn * 4];
            float4 b4 = *(float4*)&Bt[p * 64 + tc * 4];
            acc[0][0]+=a.x*b4.x; acc[0][1]+=a.x*b4.y; acc[0][2]+=a.x*b4.z; acc[0][3]+=a.x*b4.w;
            acc[1][0]+=a.y*b4.x; acc[1][1]+=a.y*b4.y; acc[1][2]+=a.y*b4.z; acc[1][3]+=a.y*b4.w;
            acc[2][0]+=a.z*b4.x; acc[2][1]+=a.z*b4.y; acc[2][2]+=a.z*b4.z; acc[2][3]+=a.z*b4.w;
            acc[3][0]+=a.w*b4.x; acc[3][1]+=a.w*b4.y; acc[3][2]+=a.w*b4.z; acc[3][3]+=a.w*b4.w;
        }
        __syncthreads();
    }
#pragma unroll
    for (int i = 0; i < 4; ++i) {
        float4 o = make_float4(acc[i][0], acc[i][1], acc[i][2], acc[i][3]);
        *(float4*)(S + ((long)(b * 64 + tn * 4 + i)) * 256 + c0 + tc * 4) = o;
    }
}

// ---------------------------------------------------------------------------
// K3: dy = kern @ Wdyn + bdyn. Output layout dyb[b][n][68]: cols 0..63 = point
// weights (j=3+m), cols 64..66 = depth weights (j=0..2). wd folded into the
// tiled chunk loop (no serial global dot phase).
// ---------------------------------------------------------------------------
__global__ __launch_bounds__(256) void dy_all(
    const float* __restrict__ kern, const float* __restrict__ Wdyn,
    const float* __restrict__ bdyn, float* __restrict__ dyb)
{
    __shared__ float Ac[16 * 64];   // [cl][n]
    __shared__ float Wc[16 * 64];   // [cl][m]
    __shared__ float Wd3[48];       // [cl][j] j<3
    const int b = blockIdx.x, t = threadIdx.x;
    const int tr = t >> 4, tc = t & 15;
    float acc[4][4];
#pragma unroll
    for (int j = 0; j < 4; ++j) {
        float bj = bdyn[3 + tc * 4 + j];
        acc[0][j] = bj; acc[1][j] = bj; acc[2][j] = bj; acc[3][j] = bj;
    }
    const int lr = t >> 2, lc = (t & 3) * 4;
    const int wl = t >> 4, wj = (t & 15) * 4;
    const int nwd = t / 3, jwd = t - nwd * 3;   // valid when t<192
    float wdacc = 0.f;
    float4 av = *(const float4*)(kern + ((long)(b * 64 + lr)) * 256 + lc);
    float w0 = Wdyn[wl * 67 + 3 + wj + 0];
    float w1 = Wdyn[wl * 67 + 3 + wj + 1];
    float w2 = Wdyn[wl * 67 + 3 + wj + 2];
    float w3 = Wdyn[wl * 67 + 3 + wj + 3];
    float wdr = (t < 48) ? Wdyn[(t / 3) * 67 + (t % 3)] : 0.f;

    for (int c0 = 0; c0 < 256; c0 += 16) {
        Ac[(lc+0)*64 + lr] = av.x; Ac[(lc+1)*64 + lr] = av.y;
        Ac[(lc+2)*64 + lr] = av.z; Ac[(lc+3)*64 + lr] = av.w;
        Wc[wl*64 + wj+0] = w0; Wc[wl*64 + wj+1] = w1;
        Wc[wl*64 + wj+2] = w2; Wc[wl*64 + wj+3] = w3;
        if (t < 48) Wd3[t] = wdr;
        __syncthreads();
        if (c0 + 16 < 256) {
            av = *(const float4*)(kern + ((long)(b * 64 + lr)) * 256 + c0 + 16 + lc);
            w0 = Wdyn[(c0 + 16 + wl) * 67 + 3 + wj + 0];
            w1 = Wdyn[(c0 + 16 + wl) * 67 + 3 + wj + 1];
            w2 = Wdyn[(c0 + 16 + wl) * 67 + 3 + wj + 2];
            w3 = Wdyn[(c0 + 16 + wl) * 67 + 3 + wj + 3];
            if (t < 48) wdr = Wdyn[(c0 + 16 + t / 3) * 67 + (t % 3)];
        }
#pragma unroll
        for (int cl = 0; cl < 16; ++cl) {
            float4 a = *(float4*)&Ac[cl * 64 + tr * 4];
            float4 w = *(float4*)&Wc[cl * 64 + tc * 4];
            acc[0][0]+=a.x*w.x; acc[0][1]+=a.x*w.y; acc[0][2]+=a.x*w.z; acc[0][3]+=a.x*w.w;
            acc[1][0]+=a.y*w.x; acc[1][1]+=a.y*w.y; acc[1][2]+=a.y*w.z; acc[1][3]+=a.y*w.w;
            acc[2][0]+=a.z*w.x; acc[2][1]+=a.z*w.y; acc[2][2]+=a.z*w.z; acc[2][3]+=a.z*w.w;
            acc[3][0]+=a.w*w.x; acc[3][1]+=a.w*w.y; acc[3][2]+=a.w*w.z; acc[3][3]+=a.w*w.w;
        }
        if (t < 192) {
#pragma unroll
            for (int cl = 0; cl < 16; ++cl)
                wdacc += Ac[cl * 64 + nwd] * Wd3[cl * 3 + jwd];
        }
        __syncthreads();
    }
#pragma unroll
    for (int i = 0; i < 4; ++i) {
        float4 o = make_float4(acc[i][0], acc[i][1], acc[i][2], acc[i][3]);
        *(float4*)(dyb + ((long)(b * 64 + tr * 4 + i)) * 68 + tc * 4) = o;
    }
    if (t < 192) dyb[((long)(b * 64 + nwd)) * 68 + 64 + jwd] = wdacc + bdyn[jwd];
}

// ---------------------------------------------------------------------------
// K4: depth conv + point GEMM per (batch, 64-channel tile). grid (4, 64).
// Emits point tile + per-row partials (sum, sumsq, sum*g*Wp).
// ---------------------------------------------------------------------------
__global__ __launch_bounds__(256) void depthpoint(
    const float* __restrict__ dyb, const float* __restrict__ v,
    const float* __restrict__ g, const float* __restrict__ Wp,
    float* __restrict__ point, float* __restrict__ partials)
{
    __shared__ float smem[13312];
    float* wpT = smem;           // [m][n] stride 68 (4352)
    float* wd3 = smem + 4352;    // [m][4] (256)
    float* vt  = smem + 4608;    // [m][lc] stride 68 (4352)
    float* dep = smem + 8960;    // [m][c_loc] stride 68 (4352)
    float* rs  = vt;             // alias: vt dead after depth phase (3*1088=3264)

    const int t = threadIdx.x;
    const int b = blockIdx.y, ct = blockIdx.x, c0 = ct * 64;
    const int tr = t >> 4, tc = t & 15;

    // stage wpT (transposed point weights)
#pragma unroll
    for (int i = 0; i < 4; ++i) {
        int idx = t + i * 256; int n = idx >> 4, m0 = (idx & 15) * 4;
        float4 w4 = *(const float4*)(dyb + ((long)(b * 64 + n)) * 68 + m0);
        wpT[(m0+0)*68 + n] = w4.x; wpT[(m0+1)*68 + n] = w4.y;
        wpT[(m0+2)*68 + n] = w4.z; wpT[(m0+3)*68 + n] = w4.w;
    }
    if (t < 64) {
        long o = ((long)(b * 64 + t)) * 68 + 64;
        wd3[t*4+0] = dyb[o+0]; wd3[t*4+1] = dyb[o+1]; wd3[t*4+2] = dyb[o+2];
    }
    // stage v tile (cols c0-1 .. c0+64, zero-padded at ends)
    {
        int m = t >> 2, lc0 = (t & 3) * 17;
#pragma unroll
        for (int k = 0; k < 17; ++k) {
            int lc = lc0 + k;
            if (lc < 66) {
                int c = c0 - 1 + lc;
                vt[m * 68 + lc] = (c >= 0 && c < 256) ? v[((long)(b * 64 + m)) * 256 + c] : 0.f;
            }
        }
    }
    __syncthreads();
    // depth conv + relu
#pragma unroll
    for (int im = 0; im < 4; ++im) {
        int m = tr * 4 + im;
        float w0 = wd3[m*4+0], w1 = wd3[m*4+1], w2 = wd3[m*4+2];
#pragma unroll
        for (int jc = 0; jc < 4; ++jc) {
            int cl = tc * 4 + jc;
            float d = w0 * vt[m*68 + cl] + w1 * vt[m*68 + cl + 1] + w2 * vt[m*68 + cl + 2];
            dep[m*68 + cl] = fmaxf(d, 0.f);
        }
    }
    __syncthreads();
    // point GEMM 4x4, K=64
    float acc[4][4] = {};
#pragma unroll 16
    for (int m = 0; m < 64; ++m) {
        float4 a4 = *(float4*)&wpT[m * 68 + tr * 4];
        float4 d4 = *(float4*)&dep[m * 68 + tc * 4];
        acc[0][0]+=a4.x*d4.x; acc[0][1]+=a4.x*d4.y; acc[0][2]+=a4.x*d4.z; acc[0][3]+=a4.x*d4.w;
        acc[1][0]+=a4.y*d4.x; acc[1][1]+=a4.y*d4.y; acc[1][2]+=a4.y*d4.z; acc[1][3]+=a4.y*d4.w;
        acc[2][0]+=a4.z*d4.x; acc[2][1]+=a4.z*d4.y; acc[2][2]+=a4.z*d4.z; acc[2][3]+=a4.z*d4.w;
        acc[3][0]+=a4.w*d4.x; acc[3][1]+=a4.w*d4.y; acc[3][2]+=a4.w*d4.z; acc[3][3]+=a4.w*d4.w;
    }
    // write point + per-row partials
    int cg = c0 + tc * 4;
    float4 g4  = *(const float4*)(g + cg);
    float4 wp4 = *(const float4*)(Wp + cg);
    float gw0 = g4.x*wp4.x, gw1 = g4.y*wp4.y, gw2 = g4.z*wp4.z, gw3 = g4.w*wp4.w;
#pragma unroll
    for (int i = 0; i < 4; ++i) {
        float4 o = make_float4(acc[i][0], acc[i][1], acc[i][2], acc[i][3]);
        *(float4*)(point + ((long)(b * 64 + tr * 4 + i)) * 256 + cg) = o;
        float s  = o.x + o.y + o.z + o.w;
        float s2 = o.x*o.x + o.y*o.y + o.z*o.z + o.w*o.w;
        float dg = o.x*gw0 + o.y*gw1 + o.z*gw2 + o.w*gw3;
        rs[0*1088 + (tr*4+i)*17 + tc] = s;
        rs[1*1088 + (tr*4+i)*17 + tc] = s2;
        rs[2*1088 + (tr*4+i)*17 + tc] = dg;
    }
    __syncthreads();
    if (t < 64) {
        float s = 0.f, s2 = 0.f, dg = 0.f;
#pragma unroll
        for (int j = 0; j < 16; ++j) {
            s  += rs[t*17 + j];
            s2 += rs[1088 + t*17 + j];
            dg += rs[2176 + t*17 + j];
        }
        long base = ((long)(b * 4 + ct)) * 192;
        partials[base + t]        = s;
        partials[base + 64 + t]   = s2;
        partials[base + 128 + t]  = dg;
    }
}

// ---------------------------------------------------------------------------
// K5: LN stats + proto (closed form) + tem from one coalesced pass over point.
// Emits murr[b][n] = (rr, -mu*rr) and AB[b] = (g_norm*tem, b_norm*tem).
// ---------------------------------------------------------------------------
__global__ __launch_bounds__(256) void lntem(
    const float* __restrict__ partials, const float* __restrict__ point,
    const float* __restrict__ g, const float* __restrict__ bta,
    const float* __restrict__ Wp, const float* __restrict__ bp,
    float* __restrict__ murr, float* __restrict__ AB)
{
    __shared__ float sA[256], sB[256];
    __shared__ float wnv[64];
    __shared__ float tot[4];
    const int b = blockIdx.x, t = threadIdx.x;
    const int c = t;
    float gc = g[c], bc = bta[c], wpc = Wp[c];
    sA[t] = gc * wpc; sB[t] = bc * wpc;
    __syncthreads();
    for (int off = 128; off >= 1; off >>= 1) {
        if (t < off) { sA[t] += sA[t+off]; sB[t] += sB[t+off]; }
        __syncthreads();
    }
    if (t == 0) { tot[0] = sA[0]; tot[1] = sB[0] + bp[0]; }
    __syncthreads();
    float Sgw = tot[0], Sbw = tot[1];

    float protoe = 0.f, mu = 0.f, rr = 0.f;
    if (t < 64) {
        float S1 = 0.f, S2 = 0.f, Sdg = 0.f;
#pragma unroll
        for (int ct = 0; ct < 4; ++ct) {
            long o = ((long)(b * 4 + ct)) * 192;
            S1 += partials[o + t]; S2 += partials[o + 64 + t]; Sdg += partials[o + 128 + t];
        }
        mu = S1 * (1.f / 256.f);
        float var = S2 * (1.f / 256.f) - mu * mu;
        rr = rsqrtf(var + EPSV);
        protoe = rr * (Sdg - mu * Sgw) + Sbw;
        wnv[t] = protoe * rr;
        murr[b * 128 + 2*t]     = rr;
        murr[b * 128 + 2*t + 1] = -mu * rr;
    }
    __syncthreads();
    sA[t] = (t < 64) ? protoe * rr * mu : 0.f;
    sB[t] = (t < 64) ? protoe : 0.f;
    __syncthreads();
    for (int off = 128; off >= 1; off >>= 1) {
        if (t < off) { sA[t] += sA[t+off]; sB[t] += sB[t+off]; }
        __syncthreads();
    }
    if (t == 0) { tot[2] = sA[0]; tot[3] = sB[0]; }
    __syncthreads();
    float Bv = tot[2], Sv = tot[3];

    const float* pcol = point + (long)b * 64 * 256 + c;
    float a0 = 0.f, a1 = 0.f, a2 = 0.f, a3 = 0.f;
#pragma unroll
    for (int n = 0; n < 64; n += 4) {
        a0 += wnv[n+0] * pcol[(n+0) * 256];
        a1 += wnv[n+1] * pcol[(n+1) * 256];
        a2 += wnv[n+2] * pcol[(n+2) * 256];
        a3 += wnv[n+3] * pcol[(n+3) * 256];
    }
    float accA = a0 + a1 + a2 + a3;
    float x = gc * (accA - Bv) + bc * Sv;
    float temv = 1.f / (1.f + expf(-x));
    AB[b * 512 + c]       = gc * temv;
    AB[b * 512 + 256 + c] = bc * temv;
}

// ---------------------------------------------------------------------------
// K6: x_corr = x_n @ (kx*tem), LN(g_ln,b_ln), relu, +x_feat. kx*tem built
// on the fly from point + murr + AB during LDS staging (never materialized).
// ---------------------------------------------------------------------------
__global__ __launch_bounds__(256) void final_kernel(
    const float* __restrict__ xn, const float* __restrict__ point,
    const float* __restrict__ murr, const float* __restrict__ AB,
    const float* __restrict__ xf, const float* __restrict__ g,
    const float* __restrict__ bt, float* __restrict__ out)
{
    __shared__ float xtT[64 * 68];  // [n][p_local]
    __shared__ float kc[64 * 68];   // [n][c_local] = kx*tem chunk
    __shared__ float rs1[64 * 17], rs2[64 * 17];
    __shared__ float mu[64], rr[64];
    __shared__ float rq[128];
    const int t = threadIdx.x;
    const int b = blockIdx.y;
    const int pg = blockIdx.x;
    const int tr = t >> 4;
    const int tc = t & 15;

    if (t < 128) rq[t] = murr[b * 128 + t];
    {
        int row = t >> 2, q = t & 3;
        const float* src = xn + ((long)(b * 1024 + pg * 64 + row)) * 64 + q * 16;
        float4 f0 = *(const float4*)(src + 0);
        float4 f1 = *(const float4*)(src + 4);
        float4 f2 = *(const float4*)(src + 8);
        float4 f3 = *(const float4*)(src + 12);
        int n0 = q * 16;
        xtT[(n0+ 0)*68+row]=f0.x; xtT[(n0+ 1)*68+row]=f0.y; xtT[(n0+ 2)*68+row]=f0.z; xtT[(n0+ 3)*68+row]=f0.w;
        xtT[(n0+ 4)*68+row]=f1.x; xtT[(n0+ 5)*68+row]=f1.y; xtT[(n0+ 6)*68+row]=f1.z; xtT[(n0+ 7)*68+row]=f1.w;
        xtT[(n0+ 8)*68+row]=f2.x; xtT[(n0+ 9)*68+row]=f2.y; xtT[(n0+10)*68+row]=f2.z; xtT[(n0+11)*68+row]=f2.w;
        xtT[(n0+12)*68+row]=f3.x; xtT[(n0+13)*68+row]=f3.y; xtT[(n0+14)*68+row]=f3.z; xtT[(n0+15)*68+row]=f3.w;
    }

    float4 xcv[4][4];
    float si[4] = {0.f,0.f,0.f,0.f}, s2i[4] = {0.f,0.f,0.f,0.f};
#pragma unroll
    for (int cc = 0; cc < 4; ++cc) {
        __syncthreads();
#pragma unroll
        for (int i = 0; i < 4; ++i) {
            int idx = t + i * 256;
            int n = idx >> 4, jq = idx & 15;
            int cb = cc * 64 + jq * 4;
            float4 p4 = *(const float4*)(point + ((long)(b * 64 + n)) * 256 + cb);
            float rn = rq[2*n], qn = rq[2*n + 1];
            float4 A4 = *(const float4*)(AB + b * 512 + cb);
            float4 B4 = *(const float4*)(AB + b * 512 + 256 + cb);
            float4 kv;
            kv.x = (p4.x * rn + qn) * A4.x + B4.x;
            kv.y = (p4.y * rn + qn) * A4.y + B4.y;
            kv.z = (p4.z * rn + qn) * A4.z + B4.z;
            kv.w = (p4.w * rn + qn) * A4.w + B4.w;
            *(float4*)&kc[n * 68 + jq * 4] = kv;
        }
        __syncthreads();
        float4 a0 = {0,0,0,0}, a1 = {0,0,0,0}, a2 = {0,0,0,0}, a3 = {0,0,0,0};
#pragma unroll 8
        for (int n = 0; n < 64; ++n) {
            float4 xv = *(float4*)&xtT[n * 68 + tr * 4];
            float4 kv = *(float4*)&kc[n * 68 + tc * 4];
            a0.x += xv.x*kv.x; a0.y += xv.x*kv.y; a0.z += xv.x*kv.z; a0.w += xv.x*kv.w;
            a1.x += xv.y*kv.x; a1.y += xv.y*kv.y; a1.z += xv.y*kv.z; a1.w += xv.y*kv.w;
            a2.x += xv.z*kv.x; a2.y += xv.z*kv.y; a2.z += xv.z*kv.z; a2.w += xv.z*kv.w;
            a3.x += xv.w*kv.x; a3.y += xv.w*kv.y; a3.z += xv.w*kv.z; a3.w += xv.w*kv.w;
        }
        xcv[cc][0] = a0; xcv[cc][1] = a1; xcv[cc][2] = a2; xcv[cc][3] = a3;
        si[0] += a0.x+a0.y+a0.z+a0.w;  s2i[0] += a0.x*a0.x+a0.y*a0.y+a0.z*a0.z+a0.w*a0.w;
        si[1] += a1.x+a1.y+a1.z+a1.w;  s2i[1] += a1.x*a1.x+a1.y*a1.y+a1.z*a1.z+a1.w*a1.w;
        si[2] += a2.x+a2.y+a2.z+a2.w;  s2i[2] += a2.x*a2.x+a2.y*a2.y+a2.z*a2.z+a2.w*a2.w;
        si[3] += a3.x+a3.y+a3.z+a3.w;  s2i[3] += a3.x*a3.x+a3.y*a3.y+a3.z*a3.z+a3.w*a3.w;
    }
#pragma unroll
    for (int i = 0; i < 4; ++i) { rs1[(tr*4+i)*17 + tc] = si[i]; rs2[(tr*4+i)*17 + tc] = s2i[i]; }
    __syncthreads();
    if (t < 64) {
        float s = 0.f, s2 = 0.f;
#pragma unroll
        for (int k = 0; k < 16; ++k) { s += rs1[t*17 + k]; s2 += rs2[t*17 + k]; }
        float m = s * (1.f / 256.f);
        mu[t] = m; rr[t] = rsqrtf(s2 * (1.f / 256.f) - m * m + EPSV);
    }
    __syncthreads();
#pragma unroll
    for (int cc = 0; cc < 4; ++cc) {
        int cb = cc * 64 + tc * 4;
        float4 g4 = *(const float4*)(g + cb);
        float4 b4 = *(const float4*)(bt + cb);
#pragma unroll
        for (int i = 0; i < 4; ++i) {
            int row = tr * 4 + i;
            float m = mu[row], r = rr[row];
            long grow = ((long)(b * 1024 + pg * 64 + row)) * 256;
            float4 xfv = *(const float4*)(xf + grow + cb);
            float4 a = xcv[cc][i];
            float4 o;
            o.x = xfv.x + fmaxf((a.x - m) * r * g4.x + b4.x, 0.f);
            o.y = xfv.y + fmaxf((a.y - m) * r * g4.y + b4.y, 0.f);
            o.z = xfv.z + fmaxf((a.z - m) * r * g4.z + b4.z, 0.f);
            o.w = xfv.w + fmaxf((a.w - m) * r * g4.w + b4.w, 0.f);
            *(float4*)(out + grow + cb) = o;
        }
    }
}

extern "C" void kernel_launch(void* const* d_in, const int* in_sizes, int n_in,
                              void* d_out, int out_size, void* d_ws, size_t ws_size,
                              hipStream_t stream)
{
    (void)in_sizes; (void)n_in; (void)out_size; (void)ws_size;
    const float* x_feat = (const float*)d_in[0];
    const float* z_feat = (const float*)d_in[1];
    const float* Wz     = (const float*)d_in[2];
    const float* bz     = (const float*)d_in[3];
    const float* Wx     = (const float*)d_in[4];
    const float* bx     = (const float*)d_in[5];
    const float* Wdyn   = (const float*)d_in[6];
    const float* bdyn   = (const float*)d_in[7];
    const float* g_norm = (const float*)d_in[8];
    const float* b_norm = (const float*)d_in[9];
    const float* Wp     = (const float*)d_in[10];
    const float* bp     = (const float*)d_in[11];
    const float* g_ln   = (const float*)d_in[12];
    const float* b_ln   = (const float*)d_in[13];
    float* out = (float*)d_out;

    float* ws       = (float*)d_ws;
    float* xn       = ws;                    // 4,194,304
    float* zc       = xn + 4194304;          // 1,048,576
    float* kern     = zc + 1048576;          // 1,048,576
    float* kxr      = kern + 1048576;        // 1,048,576
    float* point    = kxr + 1048576;         // 1,048,576
    float* dyb      = point + 1048576;       //   278,528
    float* partials = dyb + 278528;          //    49,152
    float* murr     = partials + 49152;      //     8,192
    float* AB       = murr + 8192;           //    32,768

    gemm_all<<<640, 256, 0, stream>>>(x_feat, Wx, bx, xn, z_feat, Wz, bz, zc);
    corr_all<<<dim3(4, 128), 256, 0, stream>>>(xn, x_feat, kxr, zc, z_feat, kern);
    dy_all<<<64, 256, 0, stream>>>(kern, Wdyn, bdyn, dyb);
    depthpoint<<<dim3(4, 64), 256, 0, stream>>>(dyb, kxr, g_norm, Wp, point, partials);
    lntem<<<64, 256, 0, stream>>>(partials, point, g_norm, b_norm, Wp, bp, murr, AB);
    final_kernel<<<dim3(16, 64), 256, 0, stream>>>(xn, point, murr, AB, x_feat, g_ln, b_ln, out);
}

// Round 4
// 287.883 us; speedup vs baseline: 1.1277x; 1.1277x over previous
//
#include <hip/hip_runtime.h>
#include <math.h>

#define EPSV 1e-5f

typedef __attribute__((ext_vector_type(8))) short short8;
typedef __attribute__((ext_vector_type(4))) float f32x4;

// pack two f32 -> two bf16 (RTNE) in one uint
static __device__ __forceinline__ unsigned bfpack2(float lo, float hi) {
    union { float f; unsigned u; } a, b;
    a.f = lo; b.f = hi;
    unsigned ua = a.u + 0x7fffu + ((a.u >> 16) & 1u);
    unsigned ub = b.u + 0x7fffu + ((b.u >> 16) & 1u);
    return (ua >> 16) | (ub & 0xffff0000u);
}

// ---------------------------------------------------------------------------
// K1: combined projection GEMMs, 128-row tiles. blocks 0..511 x, 512..639 z.
// Y[r][n] = sum_c X[r][c]*W[c][n] + bias[n]  (C=256, N=64).
// Also emits transposed bf16 copies for the MFMA correlation:
//   Tn[b][n][p] from the accumulators, Tf[b][c][p] from the staged Xc tiles.
// ---------------------------------------------------------------------------
__global__ __launch_bounds__(256) void gemm_all(
    const float* __restrict__ Xx, const float* __restrict__ Wxp,
    const float* __restrict__ bxp, float* __restrict__ Yx,
    const float* __restrict__ Xz, const float* __restrict__ Wzp,
    const float* __restrict__ bzp,
    unsigned short* __restrict__ xnbT, unsigned short* __restrict__ xfbT,
    unsigned short* __restrict__ zcbT, unsigned short* __restrict__ zfbT)
{
    __shared__ float Xc[16 * 132];   // [cl][row], stride 132
    __shared__ float Wc[16 * 64];    // [cl][n]
    const int t = threadIdx.x;
    const float *X, *W, *bias; float* Y;
    unsigned short *Tn, *Tf;
    long r0; int P, bb, p0;
    if (blockIdx.x < 512) {
        X = Xx; W = Wxp; bias = bxp; Y = Yx;
        r0 = (long)blockIdx.x * 128;
        P = 1024; bb = blockIdx.x >> 3; p0 = (blockIdx.x & 7) * 128;
        Tn = xnbT; Tf = xfbT;
    } else {
        int zb = blockIdx.x - 512;
        X = Xz; W = Wzp; bias = bzp; Y = nullptr;
        r0 = (long)zb * 128;
        P = 256; bb = zb >> 1; p0 = (zb & 1) * 128;
        Tn = zcbT; Tf = zfbT;
    }

    const int tr = t >> 4, tc = t & 15;   // rows tr*8..+7, cols tc*4..+3
    float4 bv = *(const float4*)(bias + tc * 4);
    float acc[8][4];
#pragma unroll
    for (int i = 0; i < 8; ++i) { acc[i][0]=bv.x; acc[i][1]=bv.y; acc[i][2]=bv.z; acc[i][3]=bv.w; }

    const int lr = t >> 2;            // 0..63 (also lr+64)
    const int lc = (t & 3) * 4;
    const int wl = t >> 4, wj = (t & 15) * 4;
    float4 xv0 = *(const float4*)(X + (r0 + lr) * 256 + lc);
    float4 xv1 = *(const float4*)(X + (r0 + lr + 64) * 256 + lc);
    float4 wv  = *(const float4*)(W + (long)wl * 64 + wj);

    for (int c0 = 0; c0 < 256; c0 += 16) {
        Xc[(lc+0)*132 + lr] = xv0.x; Xc[(lc+1)*132 + lr] = xv0.y;
        Xc[(lc+2)*132 + lr] = xv0.z; Xc[(lc+3)*132 + lr] = xv0.w;
        Xc[(lc+0)*132 + lr+64] = xv1.x; Xc[(lc+1)*132 + lr+64] = xv1.y;
        Xc[(lc+2)*132 + lr+64] = xv1.z; Xc[(lc+3)*132 + lr+64] = xv1.w;
        *(float4*)&Wc[wl * 64 + wj] = wv;
        __syncthreads();
        if (c0 + 16 < 256) {
            xv0 = *(const float4*)(X + (r0 + lr) * 256 + c0 + 16 + lc);
            xv1 = *(const float4*)(X + (r0 + lr + 64) * 256 + c0 + 16 + lc);
            wv  = *(const float4*)(W + (long)(c0 + 16 + wl) * 64 + wj);
        }
#pragma unroll
        for (int cl = 0; cl < 16; ++cl) {
            float4 a0 = *(float4*)&Xc[cl * 132 + tr * 8];
            float4 a1 = *(float4*)&Xc[cl * 132 + tr * 8 + 4];
            float4 b4 = *(float4*)&Wc[cl * 64 + tc * 4];
            acc[0][0]+=a0.x*b4.x; acc[0][1]+=a0.x*b4.y; acc[0][2]+=a0.x*b4.z; acc[0][3]+=a0.x*b4.w;
            acc[1][0]+=a0.y*b4.x; acc[1][1]+=a0.y*b4.y; acc[1][2]+=a0.y*b4.z; acc[1][3]+=a0.y*b4.w;
            acc[2][0]+=a0.z*b4.x; acc[2][1]+=a0.z*b4.y; acc[2][2]+=a0.z*b4.z; acc[2][3]+=a0.z*b4.w;
            acc[3][0]+=a0.w*b4.x; acc[3][1]+=a0.w*b4.y; acc[3][2]+=a0.w*b4.z; acc[3][3]+=a0.w*b4.w;
            acc[4][0]+=a1.x*b4.x; acc[4][1]+=a1.x*b4.y; acc[4][2]+=a1.x*b4.z; acc[4][3]+=a1.x*b4.w;
            acc[5][0]+=a1.y*b4.x; acc[5][1]+=a1.y*b4.y; acc[5][2]+=a1.y*b4.z; acc[5][3]+=a1.y*b4.w;
            acc[6][0]+=a1.z*b4.x; acc[6][1]+=a1.z*b4.y; acc[6][2]+=a1.z*b4.z; acc[6][3]+=a1.z*b4.w;
            acc[7][0]+=a1.w*b4.x; acc[7][1]+=a1.w*b4.y; acc[7][2]+=a1.w*b4.z; acc[7][3]+=a1.w*b4.w;
        }
        // transposed bf16 dump of this X chunk: Tf[bb][c0+cl][p0 + p8 .. +7]
        {
            int cl2 = t >> 4, p8 = (t & 15) * 8;
            const float* xr = &Xc[cl2 * 132 + p8];
            uint4 pk;
            pk.x = bfpack2(xr[0], xr[1]); pk.y = bfpack2(xr[2], xr[3]);
            pk.z = bfpack2(xr[4], xr[5]); pk.w = bfpack2(xr[6], xr[7]);
            *(uint4*)(Tf + ((long)(bb * 256 + c0 + cl2)) * P + p0 + p8) = pk;
        }
        __syncthreads();
    }
    if (Y) {
#pragma unroll
        for (int i = 0; i < 8; ++i) {
            float4 o = make_float4(acc[i][0], acc[i][1], acc[i][2], acc[i][3]);
            *(float4*)(Y + (r0 + tr * 8 + i) * 64 + tc * 4) = o;
        }
    }
    // transposed bf16 projection: Tn[bb][n][p0 + tr*8 .. +7]
#pragma unroll
    for (int j = 0; j < 4; ++j) {
        int n = tc * 4 + j;
        uint4 pk;
        pk.x = bfpack2(acc[0][j], acc[1][j]);
        pk.y = bfpack2(acc[2][j], acc[3][j]);
        pk.z = bfpack2(acc[4][j], acc[5][j]);
        pk.w = bfpack2(acc[6][j], acc[7][j]);
        *(uint4*)(Tn + ((long)(bb * 64 + n)) * P + p0 + tr * 8) = pk;
    }
}

// ---------------------------------------------------------------------------
// K2: correlations via bf16 MFMA. S[b][n][c] = sum_p Yn[p][n]*X[p][c].
// A = YnT (from xnbT/zcbT, [n][p]), B = XT (from xfbT/zfbT, [c][p]).
// 16x16x32 bf16 MFMA, f32 accumulate. grid (4 ctiles, 128): y<64 x-path,
// else z-path. LDS rows padded to 136 bf16 (bank rotation).
// ---------------------------------------------------------------------------
__global__ __launch_bounds__(256) void corr_mfma(
    const unsigned short* __restrict__ xnbT, const unsigned short* __restrict__ xfbT,
    float* __restrict__ kxr,
    const unsigned short* __restrict__ zcbT, const unsigned short* __restrict__ zfbT,
    float* __restrict__ kern)
{
    __shared__ __align__(16) unsigned short AT[64 * 136];
    __shared__ __align__(16) unsigned short BT[64 * 136];
    const int t = threadIdx.x;
    const unsigned short *Ab, *Bb; float* S; int b, P;
    if (blockIdx.y < 64) { b = blockIdx.y;      Ab = xnbT; Bb = xfbT; S = kxr;  P = 1024; }
    else                 { b = blockIdx.y - 64; Ab = zcbT; Bb = zfbT; S = kern; P = 256;  }
    const int ct = blockIdx.x;           // 64-channel tile
    const int w = t >> 6, l = t & 63;
    const int quad = l >> 4, lane16 = l & 15;

    const unsigned short* Abase = Ab + (long)b * 64 * P;                 // [64 n][P]
    const unsigned short* Bbase = Bb + ((long)(b * 256 + ct * 64)) * P;  // [64 c][P]
    const int srow = t >> 4, sk = (t & 15) * 8;

    f32x4 acc[4] = {{0.f,0.f,0.f,0.f},{0.f,0.f,0.f,0.f},{0.f,0.f,0.f,0.f},{0.f,0.f,0.f,0.f}};

    uint4 pa[4], pb[4];
#pragma unroll
    for (int i = 0; i < 4; ++i) {
        int row = srow + i * 16;
        pa[i] = *(const uint4*)(Abase + (long)row * P + sk);
        pb[i] = *(const uint4*)(Bbase + (long)row * P + sk);
    }
    const int nk = P >> 7;               // 128-px chunks
    for (int kc = 0; kc < nk; ++kc) {
#pragma unroll
        for (int i = 0; i < 4; ++i) {
            int row = srow + i * 16;
            *(uint4*)&AT[row * 136 + sk] = pa[i];
            *(uint4*)&BT[row * 136 + sk] = pb[i];
        }
        __syncthreads();
        if (kc + 1 < nk) {
            int ko = (kc + 1) * 128 + sk;
#pragma unroll
            for (int i = 0; i < 4; ++i) {
                int row = srow + i * 16;
                pa[i] = *(const uint4*)(Abase + (long)row * P + ko);
                pb[i] = *(const uint4*)(Bbase + (long)row * P + ko);
            }
        }
#pragma unroll
        for (int ks = 0; ks < 4; ++ks) {
            const int ko2 = ks * 32 + quad * 8;
            short8 bfrag = *(const short8*)&BT[(w * 16 + lane16) * 136 + ko2];
#pragma unroll
            for (int mi = 0; mi < 4; ++mi) {
                short8 afrag = *(const short8*)&AT[(mi * 16 + lane16) * 136 + ko2];
                acc[mi] = __builtin_amdgcn_mfma_f32_16x16x32_bf16(afrag, bfrag, acc[mi], 0, 0, 0);
            }
        }
        __syncthreads();
    }
    // C/D layout: col = lane&15 (c), row = quad*4 + reg (n within 16-tile)
#pragma unroll
    for (int mi = 0; mi < 4; ++mi) {
        long row = (long)(b * 64 + mi * 16 + quad * 4);
        int col = ct * 64 + w * 16 + lane16;
#pragma unroll
        for (int r = 0; r < 4; ++r)
            S[(row + r) * 256 + col] = acc[mi][r];
    }
}

// ---------------------------------------------------------------------------
// K3: dy = kern @ Wdyn + bdyn. dyb[b][n][68]: 0..63 point, 64..66 depth.
// ---------------------------------------------------------------------------
__global__ __launch_bounds__(256) void dy_all(
    const float* __restrict__ kern, const float* __restrict__ Wdyn,
    const float* __restrict__ bdyn, float* __restrict__ dyb)
{
    __shared__ float Ac[16 * 64];
    __shared__ float Wc[16 * 64];
    __shared__ float Wd3[48];
    const int b = blockIdx.x, t = threadIdx.x;
    const int tr = t >> 4, tc = t & 15;
    float acc[4][4];
#pragma unroll
    for (int j = 0; j < 4; ++j) {
        float bj = bdyn[3 + tc * 4 + j];
        acc[0][j] = bj; acc[1][j] = bj; acc[2][j] = bj; acc[3][j] = bj;
    }
    const int lr = t >> 2, lc = (t & 3) * 4;
    const int wl = t >> 4, wj = (t & 15) * 4;
    const int nwd = t / 3, jwd = t - nwd * 3;
    float wdacc = 0.f;
    float4 av = *(const float4*)(kern + ((long)(b * 64 + lr)) * 256 + lc);
    float w0 = Wdyn[wl * 67 + 3 + wj + 0];
    float w1 = Wdyn[wl * 67 + 3 + wj + 1];
    float w2 = Wdyn[wl * 67 + 3 + wj + 2];
    float w3 = Wdyn[wl * 67 + 3 + wj + 3];
    float wdr = (t < 48) ? Wdyn[(t / 3) * 67 + (t % 3)] : 0.f;

    for (int c0 = 0; c0 < 256; c0 += 16) {
        Ac[(lc+0)*64 + lr] = av.x; Ac[(lc+1)*64 + lr] = av.y;
        Ac[(lc+2)*64 + lr] = av.z; Ac[(lc+3)*64 + lr] = av.w;
        Wc[wl*64 + wj+0] = w0; Wc[wl*64 + wj+1] = w1;
        Wc[wl*64 + wj+2] = w2; Wc[wl*64 + wj+3] = w3;
        if (t < 48) Wd3[t] = wdr;
        __syncthreads();
        if (c0 + 16 < 256) {
            av = *(const float4*)(kern + ((long)(b * 64 + lr)) * 256 + c0 + 16 + lc);
            w0 = Wdyn[(c0 + 16 + wl) * 67 + 3 + wj + 0];
            w1 = Wdyn[(c0 + 16 + wl) * 67 + 3 + wj + 1];
            w2 = Wdyn[(c0 + 16 + wl) * 67 + 3 + wj + 2];
            w3 = Wdyn[(c0 + 16 + wl) * 67 + 3 + wj + 3];
            if (t < 48) wdr = Wdyn[(c0 + 16 + t / 3) * 67 + (t % 3)];
        }
#pragma unroll
        for (int cl = 0; cl < 16; ++cl) {
            float4 a = *(float4*)&Ac[cl * 64 + tr * 4];
            float4 w = *(float4*)&Wc[cl * 64 + tc * 4];
            acc[0][0]+=a.x*w.x; acc[0][1]+=a.x*w.y; acc[0][2]+=a.x*w.z; acc[0][3]+=a.x*w.w;
            acc[1][0]+=a.y*w.x; acc[1][1]+=a.y*w.y; acc[1][2]+=a.y*w.z; acc[1][3]+=a.y*w.w;
            acc[2][0]+=a.z*w.x; acc[2][1]+=a.z*w.y; acc[2][2]+=a.z*w.z; acc[2][3]+=a.z*w.w;
            acc[3][0]+=a.w*w.x; acc[3][1]+=a.w*w.y; acc[3][2]+=a.w*w.z; acc[3][3]+=a.w*w.w;
        }
        if (t < 192) {
#pragma unroll
            for (int cl = 0; cl < 16; ++cl)
                wdacc += Ac[cl * 64 + nwd] * Wd3[cl * 3 + jwd];
        }
        __syncthreads();
    }
#pragma unroll
    for (int i = 0; i < 4; ++i) {
        float4 o = make_float4(acc[i][0], acc[i][1], acc[i][2], acc[i][3]);
        *(float4*)(dyb + ((long)(b * 64 + tr * 4 + i)) * 68 + tc * 4) = o;
    }
    if (t < 192) dyb[((long)(b * 64 + nwd)) * 68 + 64 + jwd] = wdacc + bdyn[jwd];
}

// ---------------------------------------------------------------------------
// K4: depth conv + point GEMM per (batch, 64-channel tile). grid (4, 64).
// ---------------------------------------------------------------------------
__global__ __launch_bounds__(256) void depthpoint(
    const float* __restrict__ dyb, const float* __restrict__ v,
    const float* __restrict__ g, const float* __restrict__ Wp,
    float* __restrict__ point, float* __restrict__ partials)
{
    __shared__ float smem[13312];
    float* wpT = smem;           // [m][n] stride 68
    float* wd3 = smem + 4352;    // [m][4]
    float* vt  = smem + 4608;    // [m][lc] stride 68
    float* dep = smem + 8960;    // [m][c_loc] stride 68
    float* rs  = vt;             // alias after depth phase

    const int t = threadIdx.x;
    const int b = blockIdx.y, ct = blockIdx.x, c0 = ct * 64;
    const int tr = t >> 4, tc = t & 15;

#pragma unroll
    for (int i = 0; i < 4; ++i) {
        int idx = t + i * 256; int n = idx >> 4, m0 = (idx & 15) * 4;
        float4 w4 = *(const float4*)(dyb + ((long)(b * 64 + n)) * 68 + m0);
        wpT[(m0+0)*68 + n] = w4.x; wpT[(m0+1)*68 + n] = w4.y;
        wpT[(m0+2)*68 + n] = w4.z; wpT[(m0+3)*68 + n] = w4.w;
    }
    if (t < 64) {
        long o = ((long)(b * 64 + t)) * 68 + 64;
        wd3[t*4+0] = dyb[o+0]; wd3[t*4+1] = dyb[o+1]; wd3[t*4+2] = dyb[o+2];
    }
    {
        int m = t >> 2, lc0 = (t & 3) * 17;
#pragma unroll
        for (int k = 0; k < 17; ++k) {
            int lc = lc0 + k;
            if (lc < 66) {
                int c = c0 - 1 + lc;
                vt[m * 68 + lc] = (c >= 0 && c < 256) ? v[((long)(b * 64 + m)) * 256 + c] : 0.f;
            }
        }
    }
    __syncthreads();
#pragma unroll
    for (int im = 0; im < 4; ++im) {
        int m = tr * 4 + im;
        float w0 = wd3[m*4+0], w1 = wd3[m*4+1], w2 = wd3[m*4+2];
#pragma unroll
        for (int jc = 0; jc < 4; ++jc) {
            int cl = tc * 4 + jc;
            float d = w0 * vt[m*68 + cl] + w1 * vt[m*68 + cl + 1] + w2 * vt[m*68 + cl + 2];
            dep[m*68 + cl] = fmaxf(d, 0.f);
        }
    }
    __syncthreads();
    float acc[4][4] = {};
#pragma unroll 16
    for (int m = 0; m < 64; ++m) {
        float4 a4 = *(float4*)&wpT[m * 68 + tr * 4];
        float4 d4 = *(float4*)&dep[m * 68 + tc * 4];
        acc[0][0]+=a4.x*d4.x; acc[0][1]+=a4.x*d4.y; acc[0][2]+=a4.x*d4.z; acc[0][3]+=a4.x*d4.w;
        acc[1][0]+=a4.y*d4.x; acc[1][1]+=a4.y*d4.y; acc[1][2]+=a4.y*d4.z; acc[1][3]+=a4.y*d4.w;
        acc[2][0]+=a4.z*d4.x; acc[2][1]+=a4.z*d4.y; acc[2][2]+=a4.z*d4.z; acc[2][3]+=a4.z*d4.w;
        acc[3][0]+=a4.w*d4.x; acc[3][1]+=a4.w*d4.y; acc[3][2]+=a4.w*d4.z; acc[3][3]+=a4.w*d4.w;
    }
    int cg = c0 + tc * 4;
    float4 g4  = *(const float4*)(g + cg);
    float4 wp4 = *(const float4*)(Wp + cg);
    float gw0 = g4.x*wp4.x, gw1 = g4.y*wp4.y, gw2 = g4.z*wp4.z, gw3 = g4.w*wp4.w;
#pragma unroll
    for (int i = 0; i < 4; ++i) {
        float4 o = make_float4(acc[i][0], acc[i][1], acc[i][2], acc[i][3]);
        *(float4*)(point + ((long)(b * 64 + tr * 4 + i)) * 256 + cg) = o;
        float s  = o.x + o.y + o.z + o.w;
        float s2 = o.x*o.x + o.y*o.y + o.z*o.z + o.w*o.w;
        float dg = o.x*gw0 + o.y*gw1 + o.z*gw2 + o.w*gw3;
        rs[0*1088 + (tr*4+i)*17 + tc] = s;
        rs[1*1088 + (tr*4+i)*17 + tc] = s2;
        rs[2*1088 + (tr*4+i)*17 + tc] = dg;
    }
    __syncthreads();
    if (t < 64) {
        float s = 0.f, s2 = 0.f, dg = 0.f;
#pragma unroll
        for (int j = 0; j < 16; ++j) {
            s  += rs[t*17 + j];
            s2 += rs[1088 + t*17 + j];
            dg += rs[2176 + t*17 + j];
        }
        long base = ((long)(b * 4 + ct)) * 192;
        partials[base + t]        = s;
        partials[base + 64 + t]   = s2;
        partials[base + 128 + t]  = dg;
    }
}

// ---------------------------------------------------------------------------
// K5: LN stats + proto (closed form) + tem. Emits murr[b][n]=(rr,-mu*rr),
// AB[b] = (g_norm*tem, b_norm*tem).
// ---------------------------------------------------------------------------
__global__ __launch_bounds__(256) void lntem(
    const float* __restrict__ partials, const float* __restrict__ point,
    const float* __restrict__ g, const float* __restrict__ bta,
    const float* __restrict__ Wp, const float* __restrict__ bp,
    float* __restrict__ murr, float* __restrict__ AB)
{
    __shared__ float sA[256], sB[256];
    __shared__ float wnv[64];
    __shared__ float tot[4];
    const int b = blockIdx.x, t = threadIdx.x;
    const int c = t;
    float gc = g[c], bc = bta[c], wpc = Wp[c];
    sA[t] = gc * wpc; sB[t] = bc * wpc;
    __syncthreads();
    for (int off = 128; off >= 1; off >>= 1) {
        if (t < off) { sA[t] += sA[t+off]; sB[t] += sB[t+off]; }
        __syncthreads();
    }
    if (t == 0) { tot[0] = sA[0]; tot[1] = sB[0] + bp[0]; }
    __syncthreads();
    float Sgw = tot[0], Sbw = tot[1];

    float protoe = 0.f, mu = 0.f, rr = 0.f;
    if (t < 64) {
        float S1 = 0.f, S2 = 0.f, Sdg = 0.f;
#pragma unroll
        for (int ct = 0; ct < 4; ++ct) {
            long o = ((long)(b * 4 + ct)) * 192;
            S1 += partials[o + t]; S2 += partials[o + 64 + t]; Sdg += partials[o + 128 + t];
        }
        mu = S1 * (1.f / 256.f);
        float var = S2 * (1.f / 256.f) - mu * mu;
        rr = rsqrtf(var + EPSV);
        protoe = rr * (Sdg - mu * Sgw) + Sbw;
        wnv[t] = protoe * rr;
        murr[b * 128 + 2*t]     = rr;
        murr[b * 128 + 2*t + 1] = -mu * rr;
    }
    __syncthreads();
    sA[t] = (t < 64) ? protoe * rr * mu : 0.f;
    sB[t] = (t < 64) ? protoe : 0.f;
    __syncthreads();
    for (int off = 128; off >= 1; off >>= 1) {
        if (t < off) { sA[t] += sA[t+off]; sB[t] += sB[t+off]; }
        __syncthreads();
    }
    if (t == 0) { tot[2] = sA[0]; tot[3] = sB[0]; }
    __syncthreads();
    float Bv = tot[2], Sv = tot[3];

    const float* pcol = point + (long)b * 64 * 256 + c;
    float a0 = 0.f, a1 = 0.f, a2 = 0.f, a3 = 0.f;
#pragma unroll
    for (int n = 0; n < 64; n += 4) {
        a0 += wnv[n+0] * pcol[(n+0) * 256];
        a1 += wnv[n+1] * pcol[(n+1) * 256];
        a2 += wnv[n+2] * pcol[(n+2) * 256];
        a3 += wnv[n+3] * pcol[(n+3) * 256];
    }
    float accA = a0 + a1 + a2 + a3;
    float x = gc * (accA - Bv) + bc * Sv;
    float temv = 1.f / (1.f + expf(-x));
    AB[b * 512 + c]       = gc * temv;
    AB[b * 512 + 256 + c] = bc * temv;
}

// ---------------------------------------------------------------------------
// K6: x_corr = x_n @ (kx*tem), LN, relu, +x_feat. kx*tem built on the fly.
// ---------------------------------------------------------------------------
__global__ __launch_bounds__(256) void final_kernel(
    const float* __restrict__ xn, const float* __restrict__ point,
    const float* __restrict__ murr, const float* __restrict__ AB,
    const float* __restrict__ xf, const float* __restrict__ g,
    const float* __restrict__ bt, float* __restrict__ out)
{
    __shared__ float xtT[64 * 68];
    __shared__ float kc[64 * 68];
    __shared__ float rs1[64 * 17], rs2[64 * 17];
    __shared__ float mu[64], rr[64];
    __shared__ float rq[128];
    const int t = threadIdx.x;
    const int b = blockIdx.y;
    const int pg = blockIdx.x;
    const int tr = t >> 4;
    const int tc = t & 15;

    if (t < 128) rq[t] = murr[b * 128 + t];
    {
        int row = t >> 2, q = t & 3;
        const float* src = xn + ((long)(b * 1024 + pg * 64 + row)) * 64 + q * 16;
        float4 f0 = *(const float4*)(src + 0);
        float4 f1 = *(const float4*)(src + 4);
        float4 f2 = *(const float4*)(src + 8);
        float4 f3 = *(const float4*)(src + 12);
        int n0 = q * 16;
        xtT[(n0+ 0)*68+row]=f0.x; xtT[(n0+ 1)*68+row]=f0.y; xtT[(n0+ 2)*68+row]=f0.z; xtT[(n0+ 3)*68+row]=f0.w;
        xtT[(n0+ 4)*68+row]=f1.x; xtT[(n0+ 5)*68+row]=f1.y; xtT[(n0+ 6)*68+row]=f1.z; xtT[(n0+ 7)*68+row]=f1.w;
        xtT[(n0+ 8)*68+row]=f2.x; xtT[(n0+ 9)*68+row]=f2.y; xtT[(n0+10)*68+row]=f2.z; xtT[(n0+11)*68+row]=f2.w;
        xtT[(n0+12)*68+row]=f3.x; xtT[(n0+13)*68+row]=f3.y; xtT[(n0+14)*68+row]=f3.z; xtT[(n0+15)*68+row]=f3.w;
    }

    float4 xcv[4][4];
    float si[4] = {0.f,0.f,0.f,0.f}, s2i[4] = {0.f,0.f,0.f,0.f};
#pragma unroll
    for (int cc = 0; cc < 4; ++cc) {
        __syncthreads();
#pragma unroll
        for (int i = 0; i < 4; ++i) {
            int idx = t + i * 256;
            int n = idx >> 4, jq = idx & 15;
            int cb = cc * 64 + jq * 4;
            float4 p4 = *(const float4*)(point + ((long)(b * 64 + n)) * 256 + cb);
            float rn = rq[2*n], qn = rq[2*n + 1];
            float4 A4 = *(const float4*)(AB + b * 512 + cb);
            float4 B4 = *(const float4*)(AB + b * 512 + 256 + cb);
            float4 kv;
            kv.x = (p4.x * rn + qn) * A4.x + B4.x;
            kv.y = (p4.y * rn + qn) * A4.y + B4.y;
            kv.z = (p4.z * rn + qn) * A4.z + B4.z;
            kv.w = (p4.w * rn + qn) * A4.w + B4.w;
            *(float4*)&kc[n * 68 + jq * 4] = kv;
        }
        __syncthreads();
        float4 a0 = {0,0,0,0}, a1 = {0,0,0,0}, a2 = {0,0,0,0}, a3 = {0,0,0,0};
#pragma unroll 8
        for (int n = 0; n < 64; ++n) {
            float4 xv = *(float4*)&xtT[n * 68 + tr * 4];
            float4 kv = *(float4*)&kc[n * 68 + tc * 4];
            a0.x += xv.x*kv.x; a0.y += xv.x*kv.y; a0.z += xv.x*kv.z; a0.w += xv.x*kv.w;
            a1.x += xv.y*kv.x; a1.y += xv.y*kv.y; a1.z += xv.y*kv.z; a1.w += xv.y*kv.w;
            a2.x += xv.z*kv.x; a2.y += xv.z*kv.y; a2.z += xv.z*kv.z; a2.w += xv.z*kv.w;
            a3.x += xv.w*kv.x; a3.y += xv.w*kv.y; a3.z += xv.w*kv.z; a3.w += xv.w*kv.w;
        }
        xcv[cc][0] = a0; xcv[cc][1] = a1; xcv[cc][2] = a2; xcv[cc][3] = a3;
        si[0] += a0.x+a0.y+a0.z+a0.w;  s2i[0] += a0.x*a0.x+a0.y*a0.y+a0.z*a0.z+a0.w*a0.w;
        si[1] += a1.x+a1.y+a1.z+a1.w;  s2i[1] += a1.x*a1.x+a1.y*a1.y+a1.z*a1.z+a1.w*a1.w;
        si[2] += a2.x+a2.y+a2.z+a2.w;  s2i[2] += a2.x*a2.x+a2.y*a2.y+a2.z*a2.z+a2.w*a2.w;
        si[3] += a3.x+a3.y+a3.z+a3.w;  s2i[3] += a3.x*a3.x+a3.y*a3.y+a3.z*a3.z+a3.w*a3.w;
    }
#pragma unroll
    for (int i = 0; i < 4; ++i) { rs1[(tr*4+i)*17 + tc] = si[i]; rs2[(tr*4+i)*17 + tc] = s2i[i]; }
    __syncthreads();
    if (t < 64) {
        float s = 0.f, s2 = 0.f;
#pragma unroll
        for (int k = 0; k < 16; ++k) { s += rs1[t*17 + k]; s2 += rs2[t*17 + k]; }
        float m = s * (1.f / 256.f);
        mu[t] = m; rr[t] = rsqrtf(s2 * (1.f / 256.f) - m * m + EPSV);
    }
    __syncthreads();
#pragma unroll
    for (int cc = 0; cc < 4; ++cc) {
        int cb = cc * 64 + tc * 4;
        float4 g4 = *(const float4*)(g + cb);
        float4 b4 = *(const float4*)(bt + cb);
#pragma unroll
        for (int i = 0; i < 4; ++i) {
            int row = tr * 4 + i;
            float m = mu[row], r = rr[row];
            long grow = ((long)(b * 1024 + pg * 64 + row)) * 256;
            float4 xfv = *(const float4*)(xf + grow + cb);
            float4 a = xcv[cc][i];
            float4 o;
            o.x = xfv.x + fmaxf((a.x - m) * r * g4.x + b4.x, 0.f);
            o.y = xfv.y + fmaxf((a.y - m) * r * g4.y + b4.y, 0.f);
            o.z = xfv.z + fmaxf((a.z - m) * r * g4.z + b4.z, 0.f);
            o.w = xfv.w + fmaxf((a.w - m) * r * g4.w + b4.w, 0.f);
            *(float4*)(out + grow + cb) = o;
        }
    }
}

extern "C" void kernel_launch(void* const* d_in, const int* in_sizes, int n_in,
                              void* d_out, int out_size, void* d_ws, size_t ws_size,
                              hipStream_t stream)
{
    (void)in_sizes; (void)n_in; (void)out_size; (void)ws_size;
    const float* x_feat = (const float*)d_in[0];
    const float* z_feat = (const float*)d_in[1];
    const float* Wz     = (const float*)d_in[2];
    const float* bz     = (const float*)d_in[3];
    const float* Wx     = (const float*)d_in[4];
    const float* bx     = (const float*)d_in[5];
    const float* Wdyn   = (const float*)d_in[6];
    const float* bdyn   = (const float*)d_in[7];
    const float* g_norm = (const float*)d_in[8];
    const float* b_norm = (const float*)d_in[9];
    const float* Wp     = (const float*)d_in[10];
    const float* bp     = (const float*)d_in[11];
    const float* g_ln   = (const float*)d_in[12];
    const float* b_ln   = (const float*)d_in[13];
    float* out = (float*)d_out;

    float* ws       = (float*)d_ws;
    float* xn       = ws;                    // 4,194,304 f32
    float* kern     = xn + 4194304;          // 1,048,576
    float* kxr      = kern + 1048576;        // 1,048,576
    float* point    = kxr + 1048576;         // 1,048,576
    float* dyb      = point + 1048576;       //   278,528
    float* partials = dyb + 278528;          //    49,152
    float* murr     = partials + 49152;      //     8,192
    float* AB       = murr + 8192;           //    32,768
    unsigned short* xnbT = (unsigned short*)(AB + 32768);  // 4,194,304 ush
    unsigned short* xfbT = xnbT + 4194304;                 // 16,777,216
    unsigned short* zcbT = xfbT + 16777216;                //  1,048,576
    unsigned short* zfbT = zcbT + 1048576;                 //  4,194,304

    gemm_all<<<640, 256, 0, stream>>>(x_feat, Wx, bx, xn, z_feat, Wz, bz,
                                      xnbT, xfbT, zcbT, zfbT);
    corr_mfma<<<dim3(4, 128), 256, 0, stream>>>(xnbT, xfbT, kxr, zcbT, zfbT, kern);
    dy_all<<<64, 256, 0, stream>>>(kern, Wdyn, bdyn, dyb);
    depthpoint<<<dim3(4, 64), 256, 0, stream>>>(dyb, kxr, g_norm, Wp, point, partials);
    lntem<<<64, 256, 0, stream>>>(partials, point, g_norm, b_norm, Wp, bp, murr, AB);
    final_kernel<<<dim3(16, 64), 256, 0, stream>>>(xn, point, murr, AB, x_feat, g_ln, b_ln, out);
}